// Round 4
// baseline (745.800 us; speedup 1.0000x reference)
//
#include <hip/hip_runtime.h>

#define NN 100000
#define NE 1250000
#define CIN 64
#define CH 64
#define CO 32
#define NG 128

// ---------------- init ----------------
static __global__ void k_zero(float* __restrict__ deg, float* __restrict__ sums) {
  int i = blockIdx.x * 256 + threadIdx.x;
  if (i < NN) deg[i] = 0.0f;
  if (i < NG * CO) sums[i] = 0.0f;
}

static __global__ void k_deg(const int* __restrict__ dst, float* __restrict__ deg) {
  int e = blockIdx.x * 256 + threadIdx.x;
  if (e < NE) atomicAdd(&deg[dst[e]], 1.0f);
}

static __global__ void k_dinv(float* __restrict__ deg) {
  int i = blockIdx.x * 256 + threadIdx.x;
  if (i < NN) deg[i] = rsqrtf(deg[i] + 1.0f);
}

static __global__ void k_edgew(const int* __restrict__ src, const int* __restrict__ dst,
                               const float* __restrict__ dinv, float* __restrict__ w) {
  int e = blockIdx.x * 256 + threadIdx.x;
  if (e < NE) w[e] = dinv[src[e]] * dinv[dst[e]];
}

// ---------------- GEMM 1: h = x @ W1  (one row per wave, lane = out channel) ----
static __global__ __launch_bounds__(256) void k_gemm1(const float* __restrict__ x,
                                                      const float* __restrict__ W,
                                                      float* __restrict__ h) {
  __shared__ float Ws[CIN * CH];
  for (int t = threadIdx.x; t < CIN * CH; t += 256) Ws[t] = W[t];
  __syncthreads();
  int wave = threadIdx.x >> 6;
  int lane = threadIdx.x & 63;
  int row = blockIdx.x * 4 + wave;  // grid sized exactly: 25000*4 = 100000
  const float4* xr = reinterpret_cast<const float4*>(x + row * CIN);
  float acc = 0.0f;
#pragma unroll
  for (int k4 = 0; k4 < CIN / 4; ++k4) {
    float4 xv = xr[k4];
    acc += xv.x * Ws[(k4 * 4 + 0) * CH + lane];
    acc += xv.y * Ws[(k4 * 4 + 1) * CH + lane];
    acc += xv.z * Ws[(k4 * 4 + 2) * CH + lane];
    acc += xv.w * Ws[(k4 * 4 + 3) * CH + lane];
  }
  h[row * CH + lane] = acc;
}

// ---------------- self-loop init of agg (full write => no memset needed) -------
static __global__ void k_self64(const float* __restrict__ h, const float* __restrict__ dinv,
                                float* __restrict__ agg) {
  int t = blockIdx.x * 256 + threadIdx.x;  // grid exact: N*64
  int i = t >> 6;
  float di = dinv[i];
  agg[t] = h[t] * di * di;
}

static __global__ void k_self32(const float* __restrict__ h, const float* __restrict__ dinv,
                                float* __restrict__ agg) {
  int t = blockIdx.x * 256 + threadIdx.x;  // grid exact: N*32
  int i = t >> 5;
  float di = dinv[i];
  agg[t] = h[t] * di * di;
}

// ---------------- edge scatter: one wave per edge (64ch) / half-wave (32ch) ----
static __global__ void k_edge64(const float* __restrict__ h, const float* __restrict__ w,
                                const int* __restrict__ src, const int* __restrict__ dst,
                                float* __restrict__ agg) {
  long long t = (long long)blockIdx.x * 256 + threadIdx.x;
  int e = (int)(t >> 6);
  if (e >= NE) return;
  int c = (int)(t & 63);
  int s = src[e], d = dst[e];
  atomicAdd(&agg[d * CH + c], h[s * CH + c] * w[e]);
}

static __global__ void k_edge32(const float* __restrict__ h, const float* __restrict__ w,
                                const int* __restrict__ src, const int* __restrict__ dst,
                                float* __restrict__ agg) {
  long long t = (long long)blockIdx.x * 256 + threadIdx.x;
  int e = (int)(t >> 5);
  if (e >= NE) return;
  int c = (int)(t & 31);
  int s = src[e], d = dst[e];
  atomicAdd(&agg[d * CO + c], h[s * CO + c] * w[e]);
}

// ---------------- GEMM 2: h2 = relu(agg1 + b1) @ W2 (half-wave per row) --------
static __global__ __launch_bounds__(256) void k_gemm2(const float* __restrict__ agg1,
                                                      const float* __restrict__ W,
                                                      const float* __restrict__ b1,
                                                      float* __restrict__ h2) {
  __shared__ float Ws[CH * CO];
  __shared__ float bs[CH];
  for (int t = threadIdx.x; t < CH * CO; t += 256) Ws[t] = W[t];
  if (threadIdx.x < CH) bs[threadIdx.x] = b1[threadIdx.x];
  __syncthreads();
  int half = threadIdx.x >> 5;  // 0..7
  int j = threadIdx.x & 31;
  int row = blockIdx.x * 8 + half;  // grid exact: 12500*8 = 100000
  const float4* ar = reinterpret_cast<const float4*>(agg1 + row * CH);
  float acc = 0.0f;
#pragma unroll
  for (int k4 = 0; k4 < CH / 4; ++k4) {
    float4 av = ar[k4];
    float v0 = av.x + bs[k4 * 4 + 0]; v0 = v0 > 0.f ? v0 : 0.f;
    float v1 = av.y + bs[k4 * 4 + 1]; v1 = v1 > 0.f ? v1 : 0.f;
    float v2 = av.z + bs[k4 * 4 + 2]; v2 = v2 > 0.f ? v2 : 0.f;
    float v3 = av.w + bs[k4 * 4 + 3]; v3 = v3 > 0.f ? v3 : 0.f;
    acc += v0 * Ws[(k4 * 4 + 0) * CO + j];
    acc += v1 * Ws[(k4 * 4 + 1) * CO + j];
    acc += v2 * Ws[(k4 * 4 + 2) * CO + j];
    acc += v3 * Ws[(k4 * 4 + 3) * CO + j];
  }
  h2[row * CO + j] = acc;
}

// ---------------- per-graph counts via binary search on sorted batch -----------
static __global__ void k_counts(const int* __restrict__ batch, float* __restrict__ counts) {
  int g = threadIdx.x;
  if (g >= NG) return;
  int lo = 0, hi = NN;
  while (lo < hi) { int m = (lo + hi) >> 1; if (batch[m] < g) lo = m + 1; else hi = m; }
  int lb = lo;
  lo = 0; hi = NN;
  while (lo < hi) { int m = (lo + hi) >> 1; if (batch[m] <= g) lo = m + 1; else hi = m; }
  counts[g] = (float)(lo - lb);
}

// ---------------- mean pool: scatter-add node rows into per-graph sums ---------
static __global__ void k_pool(const float* __restrict__ agg2, const int* __restrict__ batch,
                              const float* __restrict__ b2, float* __restrict__ sums) {
  int t = blockIdx.x * 256 + threadIdx.x;  // grid exact: N*32
  int i = t >> 5;
  int c = t & 31;
  atomicAdd(&sums[batch[i] * CO + c], agg2[t] + b2[c]);
}

static __global__ void k_final(const float* __restrict__ sums, const float* __restrict__ counts,
                               float* __restrict__ out) {
  int t = blockIdx.x * 256 + threadIdx.x;
  if (t >= NG * CO) return;
  out[t] = sums[t] / fmaxf(counts[t >> 5], 1.0f);
}

extern "C" void kernel_launch(void* const* d_in, const int* in_sizes, int n_in,
                              void* d_out, int out_size, void* d_ws, size_t ws_size,
                              hipStream_t stream) {
  const float* x  = (const float*)d_in[0];
  const int* ei   = (const int*)d_in[1];   // [2, NE] row-major: src = ei, dst = ei+NE
  const int* batch = (const int*)d_in[2];
  const float* W1 = (const float*)d_in[3];
  const float* b1 = (const float*)d_in[4];
  const float* W2 = (const float*)d_in[5];
  const float* b2 = (const float*)d_in[6];
  float* out = (float*)d_out;

  const int* src = ei;
  const int* dst = ei + NE;

  // workspace layout (floats), 256B-aligned chunks
  char* base = (char*)d_ws;
  size_t off = 0;
  auto alloc = [&](size_t nfloats) {
    float* p = (float*)(base + off);
    off += ((nfloats * 4 + 255) / 256) * 256;
    return p;
  };
  float* dinv  = alloc(NN);            // deg then in-place rsqrt
  float* we    = alloc(NE);            // per-edge norm
  float* bufA  = alloc((size_t)NN * CH);  // h1, then reused for h2
  float* bufB  = alloc((size_t)NN * CH);  // agg1, then reused for agg2
  float* sums  = alloc(NG * CO);
  float* counts = alloc(NG);

  dim3 B(256);
  // init
  k_zero<<<dim3((NN + 255) / 256), B, 0, stream>>>(dinv, sums);
  // degree + norm
  k_deg<<<dim3((NE + 255) / 256), B, 0, stream>>>(dst, dinv);
  k_dinv<<<dim3((NN + 255) / 256), B, 0, stream>>>(dinv);
  k_edgew<<<dim3((NE + 255) / 256), B, 0, stream>>>(src, dst, dinv, we);
  // layer 1
  k_gemm1<<<dim3(NN / 4), B, 0, stream>>>(x, W1, bufA);
  k_self64<<<dim3(NN * CH / 256), B, 0, stream>>>(bufA, dinv, bufB);
  k_edge64<<<dim3((int)(((long long)NE * CH + 255) / 256)), B, 0, stream>>>(bufA, we, src, dst, bufB);
  // layer 2 (bias+relu fused into GEMM2 read)
  k_gemm2<<<dim3(NN / 8), B, 0, stream>>>(bufB, W2, b1, bufA);
  k_self32<<<dim3(NN * CO / 256), B, 0, stream>>>(bufA, dinv, bufB);
  k_edge32<<<dim3((int)(((long long)NE * CO + 255) / 256)), B, 0, stream>>>(bufA, we, src, dst, bufB);
  // pool
  k_counts<<<dim3(1), dim3(128), 0, stream>>>(batch, counts);
  k_pool<<<dim3(NN * CO / 256), B, 0, stream>>>(bufB, batch, b2, sums);
  k_final<<<dim3((NG * CO + 255) / 256), B, 0, stream>>>(sums, counts, out);
}

// Round 9
// 405.200 us; speedup vs baseline: 1.8406x; 1.8406x over previous
//
#include <hip/hip_runtime.h>

#define NN 100000
#define NE 1250000
#define CIN 64
#define CH 64
#define CO 32
#define NG 128
#define NBLK ((NN + 255) / 256)   // 391

// ---------------- init ----------------
static __global__ void k_zero(int* __restrict__ degi, float* __restrict__ sums) {
  int i = blockIdx.x * 256 + threadIdx.x;
  if (i < NN) degi[i] = 0;
  if (i < NG * CO) sums[i] = 0.0f;
}

// ---------------- degree (int atomics) ----------------
static __global__ void k_deg(const int* __restrict__ dst, int* __restrict__ degi) {
  int e = blockIdx.x * 256 + threadIdx.x;
  if (e < NE) atomicAdd(&degi[dst[e]], 1);
}

// ---------------- prefix scan of degrees -> CSR row starts ----------------
static __global__ void k_scanA(const int* __restrict__ degi, int* __restrict__ bsum) {
  __shared__ int tmp[256];
  int i = blockIdx.x * 256 + threadIdx.x;
  int v = (i < NN) ? degi[i] : 0;
  tmp[threadIdx.x] = v;
  __syncthreads();
  for (int off = 128; off > 0; off >>= 1) {
    if (threadIdx.x < off) tmp[threadIdx.x] += tmp[threadIdx.x + off];
    __syncthreads();
  }
  if (threadIdx.x == 0) bsum[blockIdx.x] = tmp[0];
}

static __global__ void k_scanB(const int* __restrict__ bsum, int* __restrict__ bbase) {
  __shared__ int tmp[512];
  int t = threadIdx.x;
  int v = (t < NBLK) ? bsum[t] : 0;
  tmp[t] = v;
  __syncthreads();
  for (int off = 1; off < 512; off <<= 1) {
    int add = (t >= off) ? tmp[t - off] : 0;
    __syncthreads();
    tmp[t] += add;
    __syncthreads();
  }
  if (t < NBLK) bbase[t] = tmp[t] - v;  // exclusive
}

static __global__ void k_scanC(const int* __restrict__ degi, const int* __restrict__ bbase,
                               int* __restrict__ rowstart, int* __restrict__ cursor,
                               float* __restrict__ dinv) {
  __shared__ int tmp[256];
  int i = blockIdx.x * 256 + threadIdx.x;
  int v = (i < NN) ? degi[i] : 0;
  tmp[threadIdx.x] = v;
  __syncthreads();
  for (int off = 1; off < 256; off <<= 1) {
    int add = (threadIdx.x >= off) ? tmp[threadIdx.x - off] : 0;
    __syncthreads();
    tmp[threadIdx.x] += add;
    __syncthreads();
  }
  if (i < NN) {
    int rs = bbase[blockIdx.x] + tmp[threadIdx.x] - v;  // exclusive
    rowstart[i] = rs;
    cursor[i] = rs;
    dinv[i] = rsqrtf((float)v + 1.0f);
  }
}

// ---------------- CSR scatter: group src ids by dst ----------------
static __global__ void k_scatter(const int* __restrict__ src, const int* __restrict__ dst,
                                 int* __restrict__ cursor, int* __restrict__ csr_src) {
  int e = blockIdx.x * 256 + threadIdx.x;
  if (e < NE) {
    int d = dst[e];
    int pos = atomicAdd(&cursor[d], 1);
    csr_src[pos] = src[e];
  }
}

// ---------------- GEMM 1: h = x @ W1 (one row per wave, lane = out channel) ----
static __global__ __launch_bounds__(256) void k_gemm1(const float* __restrict__ x,
                                                      const float* __restrict__ W,
                                                      float* __restrict__ h) {
  __shared__ float Ws[CIN * CH];
  for (int t = threadIdx.x; t < CIN * CH; t += 256) Ws[t] = W[t];
  __syncthreads();
  int wave = threadIdx.x >> 6;
  int lane = threadIdx.x & 63;
  int row = blockIdx.x * 4 + wave;  // grid exact: 25000*4
  const float4* xr = reinterpret_cast<const float4*>(x + row * CIN);
  float acc = 0.0f;
#pragma unroll
  for (int k4 = 0; k4 < CIN / 4; ++k4) {
    float4 xv = xr[k4];
    acc += xv.x * Ws[(k4 * 4 + 0) * CH + lane];
    acc += xv.y * Ws[(k4 * 4 + 1) * CH + lane];
    acc += xv.z * Ws[(k4 * 4 + 2) * CH + lane];
    acc += xv.w * Ws[(k4 * 4 + 3) * CH + lane];
  }
  h[row * CH + lane] = acc;
}

// ---------------- layer-1 aggregation: gather over CSR, fused self-loop -------
static __global__ __launch_bounds__(256) void k_agg64(const float* __restrict__ h,
                                                      const float* __restrict__ dinv,
                                                      const int* __restrict__ rowstart,
                                                      const int* __restrict__ degi,
                                                      const int* __restrict__ csr_src,
                                                      float* __restrict__ agg) {
  int wave = threadIdx.x >> 6, lane = threadIdx.x & 63;
  int i = blockIdx.x * 4 + wave;  // grid exact: 25000*4
  float di = dinv[i];
  float acc = h[i * CH + lane] * di * di;  // self-loop
  int s0 = rowstart[i], n = degi[i];
  int k = 0;
  for (; k + 1 < n; k += 2) {
    int sA = csr_src[s0 + k];
    int sB = csr_src[s0 + k + 1];
    float wA = dinv[sA] * di;
    float wB = dinv[sB] * di;
    acc += wA * h[sA * CH + lane];
    acc += wB * h[sB * CH + lane];
  }
  if (k < n) {
    int sA = csr_src[s0 + k];
    acc += dinv[sA] * di * h[sA * CH + lane];
  }
  agg[i * CH + lane] = acc;
}

// ---------------- GEMM 2: h2 = relu(agg1 + b1) @ W2 (half-wave per row) -------
static __global__ __launch_bounds__(256) void k_gemm2(const float* __restrict__ agg1,
                                                      const float* __restrict__ W,
                                                      const float* __restrict__ b1,
                                                      float* __restrict__ h2) {
  __shared__ float Ws[CH * CO];
  __shared__ float bs[CH];
  for (int t = threadIdx.x; t < CH * CO; t += 256) Ws[t] = W[t];
  if (threadIdx.x < CH) bs[threadIdx.x] = b1[threadIdx.x];
  __syncthreads();
  int half = threadIdx.x >> 5;
  int j = threadIdx.x & 31;
  int row = blockIdx.x * 8 + half;  // grid exact: 12500*8
  const float4* ar = reinterpret_cast<const float4*>(agg1 + row * CH);
  float acc = 0.0f;
#pragma unroll
  for (int k4 = 0; k4 < CH / 4; ++k4) {
    float4 av = ar[k4];
    float v0 = av.x + bs[k4 * 4 + 0]; v0 = v0 > 0.f ? v0 : 0.f;
    float v1 = av.y + bs[k4 * 4 + 1]; v1 = v1 > 0.f ? v1 : 0.f;
    float v2 = av.z + bs[k4 * 4 + 2]; v2 = v2 > 0.f ? v2 : 0.f;
    float v3 = av.w + bs[k4 * 4 + 3]; v3 = v3 > 0.f ? v3 : 0.f;
    acc += v0 * Ws[(k4 * 4 + 0) * CO + j];
    acc += v1 * Ws[(k4 * 4 + 1) * CO + j];
    acc += v2 * Ws[(k4 * 4 + 2) * CO + j];
    acc += v3 * Ws[(k4 * 4 + 3) * CO + j];
  }
  h2[row * CO + j] = acc;
}

// ---- layer-2 aggregation + bias + mean-pool partial (LDS run-reduction) ------
static __global__ __launch_bounds__(256) void k_agg32pool(const float* __restrict__ h2,
                                                          const float* __restrict__ dinv,
                                                          const int* __restrict__ rowstart,
                                                          const int* __restrict__ degi,
                                                          const int* __restrict__ csr_src,
                                                          const int* __restrict__ batch,
                                                          const float* __restrict__ b2,
                                                          float* __restrict__ sums) {
  __shared__ float vals[8][CO];
  __shared__ int gid[8];
  int half = threadIdx.x >> 5;  // 0..7 (node slot)
  int c = threadIdx.x & 31;
  int i = blockIdx.x * 8 + half;  // grid exact: 12500*8
  float di = dinv[i];
  float acc = h2[i * CO + c] * di * di;  // self-loop
  int s0 = rowstart[i], n = degi[i];
  int k = 0;
  for (; k + 1 < n; k += 2) {
    int sA = csr_src[s0 + k];
    int sB = csr_src[s0 + k + 1];
    float wA = dinv[sA] * di;
    float wB = dinv[sB] * di;
    acc += wA * h2[sA * CO + c];
    acc += wB * h2[sB * CO + c];
  }
  if (k < n) {
    int sA = csr_src[s0 + k];
    acc += dinv[sA] * di * h2[sA * CO + c];
  }
  vals[half][c] = acc + b2[c];
  if (c == 0) gid[half] = batch[i];
  __syncthreads();
  if (threadIdx.x < 32) {
    int ch = threadIdx.x;
    float run = vals[0][ch];
    int g = gid[0];
    for (int s = 1; s < 8; ++s) {
      if (gid[s] == g) run += vals[s][ch];
      else { atomicAdd(&sums[g * CO + ch], run); g = gid[s]; run = vals[s][ch]; }
    }
    atomicAdd(&sums[g * CO + ch], run);
  }
}

// ---------------- per-graph counts via binary search on sorted batch ----------
static __global__ void k_counts(const int* __restrict__ batch, float* __restrict__ counts) {
  int g = threadIdx.x;
  if (g >= NG) return;
  int lo = 0, hi = NN;
  while (lo < hi) { int m = (lo + hi) >> 1; if (batch[m] < g) lo = m + 1; else hi = m; }
  int lb = lo;
  lo = 0; hi = NN;
  while (lo < hi) { int m = (lo + hi) >> 1; if (batch[m] <= g) lo = m + 1; else hi = m; }
  counts[g] = (float)(lo - lb);
}

static __global__ void k_final(const float* __restrict__ sums, const float* __restrict__ counts,
                               float* __restrict__ out) {
  int t = blockIdx.x * 256 + threadIdx.x;
  if (t >= NG * CO) return;
  out[t] = sums[t] / fmaxf(counts[t >> 5], 1.0f);
}

extern "C" void kernel_launch(void* const* d_in, const int* in_sizes, int n_in,
                              void* d_out, int out_size, void* d_ws, size_t ws_size,
                              hipStream_t stream) {
  const float* x   = (const float*)d_in[0];
  const int* ei    = (const int*)d_in[1];   // [2, NE]: src = ei, dst = ei+NE
  const int* batch = (const int*)d_in[2];
  const float* W1  = (const float*)d_in[3];
  const float* b1  = (const float*)d_in[4];
  const float* W2  = (const float*)d_in[5];
  const float* b2  = (const float*)d_in[6];
  float* out = (float*)d_out;

  const int* src = ei;
  const int* dst = ei + NE;

  char* base = (char*)d_ws;
  size_t off = 0;
  auto alloc = [&](size_t nelem) {
    void* p = (void*)(base + off);
    off += ((nelem * 4 + 255) / 256) * 256;
    return p;
  };
  int* degi      = (int*)alloc(NN);
  int* rowstart  = (int*)alloc(NN);
  int* cursor    = (int*)alloc(NN);
  float* dinv    = (float*)alloc(NN);
  int* bsum      = (int*)alloc(NBLK);
  int* bbase     = (int*)alloc(NBLK);
  int* csr_src   = (int*)alloc(NE);          // 5 MB
  float* bufA    = (float*)alloc((size_t)NN * CH);  // h1 then h2
  float* bufB    = (float*)alloc((size_t)NN * CH);  // agg1
  float* sums    = (float*)alloc(NG * CO);
  float* counts  = (float*)alloc(NG);

  dim3 B(256);
  k_zero<<<dim3(NBLK), B, 0, stream>>>(degi, sums);
  k_deg<<<dim3((NE + 255) / 256), B, 0, stream>>>(dst, degi);
  k_scanA<<<dim3(NBLK), B, 0, stream>>>(degi, bsum);
  k_scanB<<<dim3(1), dim3(512), 0, stream>>>(bsum, bbase);
  k_scanC<<<dim3(NBLK), B, 0, stream>>>(degi, bbase, rowstart, cursor, dinv);
  k_scatter<<<dim3((NE + 255) / 256), B, 0, stream>>>(src, dst, cursor, csr_src);
  // layer 1
  k_gemm1<<<dim3(NN / 4), B, 0, stream>>>(x, W1, bufA);
  k_agg64<<<dim3(NN / 4), B, 0, stream>>>(bufA, dinv, rowstart, degi, csr_src, bufB);
  // layer 2
  k_gemm2<<<dim3(NN / 8), B, 0, stream>>>(bufB, W2, b1, bufA);
  k_agg32pool<<<dim3(NN / 8), B, 0, stream>>>(bufA, dinv, rowstart, degi, csr_src, batch, b2, sums);
  // pool finalize
  k_counts<<<dim3(1), dim3(128), 0, stream>>>(batch, counts);
  k_final<<<dim3((NG * CO + 255) / 256), B, 0, stream>>>(sums, counts, out);
}

// Round 10
// 360.603 us; speedup vs baseline: 2.0682x; 1.1237x over previous
//
#include <hip/hip_runtime.h>

#define NN 100000
#define NE 1250000
#define CIN 64
#define CH 64
#define CO 32
#define NG 128
#define NBLK ((NN + 255) / 256)   // 391

// ---------------- init + per-graph counts (block 0) ----------------
static __global__ void k_zero(int* __restrict__ degi, float* __restrict__ sums,
                              const int* __restrict__ batch, float* __restrict__ counts) {
  int i = blockIdx.x * 256 + threadIdx.x;
  if (i < NN) degi[i] = 0;
  if (i < NG * CO) sums[i] = 0.0f;
  if (blockIdx.x == 0 && threadIdx.x < NG) {
    int g = threadIdx.x;
    int lo = 0, hi = NN;
    while (lo < hi) { int m = (lo + hi) >> 1; if (batch[m] < g) lo = m + 1; else hi = m; }
    int lb = lo;
    lo = 0; hi = NN;
    while (lo < hi) { int m = (lo + hi) >> 1; if (batch[m] <= g) lo = m + 1; else hi = m; }
    counts[g] = (float)(lo - lb);
  }
}

// ---------------- degree (int atomics) ----------------
static __global__ void k_deg(const int* __restrict__ dst, int* __restrict__ degi) {
  int e = blockIdx.x * 256 + threadIdx.x;
  if (e < NE) atomicAdd(&degi[dst[e]], 1);
}

// ---------------- prefix scan of degrees -> CSR row starts ----------------
static __global__ void k_scanA(const int* __restrict__ degi, int* __restrict__ bsum) {
  __shared__ int tmp[256];
  int i = blockIdx.x * 256 + threadIdx.x;
  int v = (i < NN) ? degi[i] : 0;
  tmp[threadIdx.x] = v;
  __syncthreads();
  for (int off = 128; off > 0; off >>= 1) {
    if (threadIdx.x < off) tmp[threadIdx.x] += tmp[threadIdx.x + off];
    __syncthreads();
  }
  if (threadIdx.x == 0) bsum[blockIdx.x] = tmp[0];
}

static __global__ void k_scanB(const int* __restrict__ bsum, int* __restrict__ bbase) {
  __shared__ int tmp[512];
  int t = threadIdx.x;
  int v = (t < NBLK) ? bsum[t] : 0;
  tmp[t] = v;
  __syncthreads();
  for (int off = 1; off < 512; off <<= 1) {
    int add = (t >= off) ? tmp[t - off] : 0;
    __syncthreads();
    tmp[t] += add;
    __syncthreads();
  }
  if (t < NBLK) bbase[t] = tmp[t] - v;  // exclusive
}

static __global__ void k_scanC(const int* __restrict__ degi, const int* __restrict__ bbase,
                               int* __restrict__ rowstart, int* __restrict__ cursor,
                               float* __restrict__ dinv) {
  __shared__ int tmp[256];
  int i = blockIdx.x * 256 + threadIdx.x;
  int v = (i < NN) ? degi[i] : 0;
  tmp[threadIdx.x] = v;
  __syncthreads();
  for (int off = 1; off < 256; off <<= 1) {
    int add = (threadIdx.x >= off) ? tmp[threadIdx.x - off] : 0;
    __syncthreads();
    tmp[threadIdx.x] += add;
    __syncthreads();
  }
  if (i < NN) {
    int rs = bbase[blockIdx.x] + tmp[threadIdx.x] - v;  // exclusive
    rowstart[i] = rs;
    cursor[i] = rs;
    dinv[i] = rsqrtf((float)v + 1.0f);
  }
}

// ---------------- CSR scatter: group src ids by dst ----------------
static __global__ void k_scatter(const int* __restrict__ src, const int* __restrict__ dst,
                                 int* __restrict__ cursor, int* __restrict__ csr_src) {
  int e = blockIdx.x * 256 + threadIdx.x;
  if (e < NE) {
    int d = dst[e];
    int pos = atomicAdd(&cursor[d], 1);
    csr_src[pos] = src[e];
  }
}

// -------- GEMM 1: h' = dinv * (x @ W1)  (one row per wave, lane = out ch) -----
static __global__ __launch_bounds__(256) void k_gemm1(const float* __restrict__ x,
                                                      const float* __restrict__ W,
                                                      const float* __restrict__ dinv,
                                                      float* __restrict__ h) {
  __shared__ float Ws[CIN * CH];
  for (int t = threadIdx.x; t < CIN * CH; t += 256) Ws[t] = W[t];
  __syncthreads();
  int wave = threadIdx.x >> 6;
  int lane = threadIdx.x & 63;
  int row = blockIdx.x * 4 + wave;  // grid exact: 25000*4
  const float4* xr = reinterpret_cast<const float4*>(x + row * CIN);
  float acc = 0.0f;
#pragma unroll
  for (int k4 = 0; k4 < CIN / 4; ++k4) {
    float4 xv = xr[k4];
    acc += xv.x * Ws[(k4 * 4 + 0) * CH + lane];
    acc += xv.y * Ws[(k4 * 4 + 1) * CH + lane];
    acc += xv.z * Ws[(k4 * 4 + 2) * CH + lane];
    acc += xv.w * Ws[(k4 * 4 + 3) * CH + lane];
  }
  h[row * CH + lane] = acc * dinv[row];
}

// ------- layer-1 agg: agg[i] = dinv[i] * (h'[i] + sum_{s in N(i)} h'[s]) ------
static __global__ __launch_bounds__(256) void k_agg64(const float* __restrict__ h,
                                                      const float* __restrict__ dinv,
                                                      const int* __restrict__ rowstart,
                                                      const int* __restrict__ degi,
                                                      const int* __restrict__ csr_src,
                                                      float* __restrict__ agg) {
  int wave = threadIdx.x >> 6, lane = threadIdx.x & 63;
  int i = blockIdx.x * 4 + wave;  // grid exact: 25000*4
  float acc = h[i * CH + lane];   // self-loop (h already dinv-scaled)
  int s0 = rowstart[i], n = degi[i];
  int k = 0;
  for (; k + 3 < n; k += 4) {
    int sA = csr_src[s0 + k];
    int sB = csr_src[s0 + k + 1];
    int sC = csr_src[s0 + k + 2];
    int sD = csr_src[s0 + k + 3];
    float a = h[sA * CH + lane];
    float b = h[sB * CH + lane];
    float c = h[sC * CH + lane];
    float d = h[sD * CH + lane];
    acc += (a + b) + (c + d);
  }
  for (; k < n; ++k) acc += h[csr_src[s0 + k] * CH + lane];
  agg[i * CH + lane] = acc * dinv[i];
}

// ------ GEMM 2: h2' = dinv * (relu(agg1 + b1) @ W2) (half-wave per row) -------
static __global__ __launch_bounds__(256) void k_gemm2(const float* __restrict__ agg1,
                                                      const float* __restrict__ W,
                                                      const float* __restrict__ b1,
                                                      const float* __restrict__ dinv,
                                                      float* __restrict__ h2) {
  __shared__ float Ws[CH * CO];
  __shared__ float bs[CH];
  for (int t = threadIdx.x; t < CH * CO; t += 256) Ws[t] = W[t];
  if (threadIdx.x < CH) bs[threadIdx.x] = b1[threadIdx.x];
  __syncthreads();
  int half = threadIdx.x >> 5;
  int j = threadIdx.x & 31;
  int row = blockIdx.x * 8 + half;  // grid exact: 12500*8
  const float4* ar = reinterpret_cast<const float4*>(agg1 + row * CH);
  float acc = 0.0f;
#pragma unroll
  for (int k4 = 0; k4 < CH / 4; ++k4) {
    float4 av = ar[k4];
    float v0 = av.x + bs[k4 * 4 + 0]; v0 = v0 > 0.f ? v0 : 0.f;
    float v1 = av.y + bs[k4 * 4 + 1]; v1 = v1 > 0.f ? v1 : 0.f;
    float v2 = av.z + bs[k4 * 4 + 2]; v2 = v2 > 0.f ? v2 : 0.f;
    float v3 = av.w + bs[k4 * 4 + 3]; v3 = v3 > 0.f ? v3 : 0.f;
    acc += v0 * Ws[(k4 * 4 + 0) * CO + j];
    acc += v1 * Ws[(k4 * 4 + 1) * CO + j];
    acc += v2 * Ws[(k4 * 4 + 2) * CO + j];
    acc += v3 * Ws[(k4 * 4 + 3) * CO + j];
  }
  h2[row * CO + j] = acc * dinv[row];
}

// ---- layer-2 agg + bias + mean-pool partial (LDS run-reduction) --------------
static __global__ __launch_bounds__(256) void k_agg32pool(const float* __restrict__ h2,
                                                          const float* __restrict__ dinv,
                                                          const int* __restrict__ rowstart,
                                                          const int* __restrict__ degi,
                                                          const int* __restrict__ csr_src,
                                                          const int* __restrict__ batch,
                                                          const float* __restrict__ b2,
                                                          float* __restrict__ sums) {
  __shared__ float vals[8][CO];
  __shared__ int gid[8];
  int half = threadIdx.x >> 5;  // 0..7 (node slot)
  int c = threadIdx.x & 31;
  int i = blockIdx.x * 8 + half;  // grid exact: 12500*8
  float acc = h2[i * CO + c];     // self-loop (h2 already dinv-scaled)
  int s0 = rowstart[i], n = degi[i];
  int k = 0;
  for (; k + 3 < n; k += 4) {
    int sA = csr_src[s0 + k];
    int sB = csr_src[s0 + k + 1];
    int sC = csr_src[s0 + k + 2];
    int sD = csr_src[s0 + k + 3];
    float a = h2[sA * CO + c];
    float b = h2[sB * CO + c];
    float cc = h2[sC * CO + c];
    float d = h2[sD * CO + c];
    acc += (a + b) + (cc + d);
  }
  for (; k < n; ++k) acc += h2[csr_src[s0 + k] * CO + c];
  vals[half][c] = acc * dinv[i] + b2[c];
  if (c == 0) gid[half] = batch[i];
  __syncthreads();
  if (threadIdx.x < 32) {
    int ch = threadIdx.x;
    float run = vals[0][ch];
    int g = gid[0];
    for (int s = 1; s < 8; ++s) {
      if (gid[s] == g) run += vals[s][ch];
      else { atomicAdd(&sums[g * CO + ch], run); g = gid[s]; run = vals[s][ch]; }
    }
    atomicAdd(&sums[g * CO + ch], run);
  }
}

static __global__ void k_final(const float* __restrict__ sums, const float* __restrict__ counts,
                               float* __restrict__ out) {
  int t = blockIdx.x * 256 + threadIdx.x;
  if (t >= NG * CO) return;
  out[t] = sums[t] / fmaxf(counts[t >> 5], 1.0f);
}

extern "C" void kernel_launch(void* const* d_in, const int* in_sizes, int n_in,
                              void* d_out, int out_size, void* d_ws, size_t ws_size,
                              hipStream_t stream) {
  const float* x   = (const float*)d_in[0];
  const int* ei    = (const int*)d_in[1];   // [2, NE]: src = ei, dst = ei+NE
  const int* batch = (const int*)d_in[2];
  const float* W1  = (const float*)d_in[3];
  const float* b1  = (const float*)d_in[4];
  const float* W2  = (const float*)d_in[5];
  const float* b2  = (const float*)d_in[6];
  float* out = (float*)d_out;

  const int* src = ei;
  const int* dst = ei + NE;

  char* base = (char*)d_ws;
  size_t off = 0;
  auto alloc = [&](size_t nelem) {
    void* p = (void*)(base + off);
    off += ((nelem * 4 + 255) / 256) * 256;
    return p;
  };
  int* degi      = (int*)alloc(NN);
  int* rowstart  = (int*)alloc(NN);
  int* cursor    = (int*)alloc(NN);
  float* dinv    = (float*)alloc(NN);
  int* bsum      = (int*)alloc(NBLK);
  int* bbase     = (int*)alloc(NBLK);
  int* csr_src   = (int*)alloc(NE);          // 5 MB
  float* bufA    = (float*)alloc((size_t)NN * CH);  // h1' then h2'
  float* bufB    = (float*)alloc((size_t)NN * CH);  // agg1
  float* sums    = (float*)alloc(NG * CO);
  float* counts  = (float*)alloc(NG);

  dim3 B(256);
  k_zero<<<dim3(NBLK), B, 0, stream>>>(degi, sums, batch, counts);
  k_deg<<<dim3((NE + 255) / 256), B, 0, stream>>>(dst, degi);
  k_scanA<<<dim3(NBLK), B, 0, stream>>>(degi, bsum);
  k_scanB<<<dim3(1), dim3(512), 0, stream>>>(bsum, bbase);
  k_scanC<<<dim3(NBLK), B, 0, stream>>>(degi, bbase, rowstart, cursor, dinv);
  k_scatter<<<dim3((NE + 255) / 256), B, 0, stream>>>(src, dst, cursor, csr_src);
  // layer 1
  k_gemm1<<<dim3(NN / 4), B, 0, stream>>>(x, W1, dinv, bufA);
  k_agg64<<<dim3(NN / 4), B, 0, stream>>>(bufA, dinv, rowstart, degi, csr_src, bufB);
  // layer 2
  k_gemm2<<<dim3(NN / 8), B, 0, stream>>>(bufB, W2, b1, dinv, bufA);
  k_agg32pool<<<dim3(NN / 8), B, 0, stream>>>(bufA, dinv, rowstart, degi, csr_src, batch, b2, sums);
  // finalize
  k_final<<<dim3((NG * CO + 255) / 256), B, 0, stream>>>(sums, counts, out);
}

// Round 11
// 298.138 us; speedup vs baseline: 2.5015x; 1.2095x over previous
//
#include <hip/hip_runtime.h>

#define NN 100000
#define NE 1250000
#define CIN 64
#define CH 64
#define CO 32
#define NG 128
#define NBLK ((NN + 255) / 256)    // 391 (node-grid for scans)
#define NBUCK 98                    // buckets of 1024 nodes: dst>>10 in [0,97]
#define BSHIFT 10
#define EPB 2048                    // edges per partition block
#define NBLKP ((NE + EPB - 1) / EPB) // 611

// ---------------- init: zero sums+bhist, per-graph counts (block 0) -----------
static __global__ void k_zero(float* __restrict__ sums, int* __restrict__ bhist,
                              const int* __restrict__ batch, float* __restrict__ counts) {
  int i = blockIdx.x * 256 + threadIdx.x;
  if (i < NG * CO) sums[i] = 0.0f;
  if (i < 128) bhist[i] = 0;
  if (blockIdx.x == 0 && threadIdx.x < NG) {
    int g = threadIdx.x;
    int lo = 0, hi = NN;
    while (lo < hi) { int m = (lo + hi) >> 1; if (batch[m] < g) lo = m + 1; else hi = m; }
    int lb = lo;
    lo = 0; hi = NN;
    while (lo < hi) { int m = (lo + hi) >> 1; if (batch[m] <= g) lo = m + 1; else hi = m; }
    counts[g] = (float)(lo - lb);
  }
}

// ---------------- bucket histogram (LDS-staged) ----------------
static __global__ __launch_bounds__(256) void k_bhist(const int* __restrict__ dst,
                                                      int* __restrict__ bhist) {
  __shared__ int lh[128];
  if (threadIdx.x < 128) lh[threadIdx.x] = 0;
  __syncthreads();
  int e0 = blockIdx.x * EPB, e1 = min(e0 + EPB, NE);
  for (int e = e0 + threadIdx.x; e < e1; e += 256)
    atomicAdd(&lh[dst[e] >> BSHIFT], 1);
  __syncthreads();
  if (threadIdx.x < 128) { int v = lh[threadIdx.x]; if (v) atomicAdd(&bhist[threadIdx.x], v); }
}

// ---------------- exclusive scan of bucket counts (1 block, 128 thr) ----------
static __global__ void k_bscan(const int* __restrict__ bhist, int* __restrict__ bbase,
                               int* __restrict__ bcursor) {
  __shared__ int tmp[128];
  int t = threadIdx.x;
  int v = bhist[t];
  tmp[t] = v;
  __syncthreads();
  for (int off = 1; off < 128; off <<= 1) {
    int a = (t >= off) ? tmp[t - off] : 0;
    __syncthreads();
    tmp[t] += a;
    __syncthreads();
  }
  int ex = tmp[t] - v;
  bbase[t] = ex;
  bcursor[t] = ex;
  if (t == 127) bbase[128] = tmp[127];  // == NE
}

// ------- partition edges into bucket-grouped (src,dst) pair runs --------------
static __global__ __launch_bounds__(256) void k_part(const int* __restrict__ src,
                                                     const int* __restrict__ dst,
                                                     int* __restrict__ bcursor,
                                                     int2* __restrict__ pairs) {
  __shared__ int lh[128], lbase[128], loff[128];
  if (threadIdx.x < 128) { lh[threadIdx.x] = 0; loff[threadIdx.x] = 0; }
  __syncthreads();
  int e0 = blockIdx.x * EPB, e1 = min(e0 + EPB, NE);
  for (int e = e0 + threadIdx.x; e < e1; e += 256)
    atomicAdd(&lh[dst[e] >> BSHIFT], 1);
  __syncthreads();
  if (threadIdx.x < 128) {
    int v = lh[threadIdx.x];
    lbase[threadIdx.x] = v ? atomicAdd(&bcursor[threadIdx.x], v) : 0;
  }
  __syncthreads();
  for (int e = e0 + threadIdx.x; e < e1; e += 256) {
    int d = dst[e], b = d >> BSHIFT;
    int o = atomicAdd(&loff[b], 1);
    pairs[lbase[b] + o] = make_int2(src[e], d);
  }
}

// ------- per-bucket degree via LDS histogram; coalesced degi/dinv writes ------
static __global__ __launch_bounds__(256) void k_bucket_a(const int2* __restrict__ pairs,
                                                         const int* __restrict__ bbase,
                                                         int* __restrict__ degi,
                                                         float* __restrict__ dinv) {
  __shared__ int lh[1024];
  for (int t = threadIdx.x; t < 1024; t += 256) lh[t] = 0;
  __syncthreads();
  int b = blockIdx.x;
  int p0 = bbase[b], p1 = bbase[b + 1];
  for (int p = p0 + threadIdx.x; p < p1; p += 256)
    atomicAdd(&lh[pairs[p].y & 1023], 1);
  __syncthreads();
  int nb = b << BSHIFT;
  for (int t = threadIdx.x; t < 1024; t += 256) {
    int node = nb + t;
    if (node < NN) { int dg = lh[t]; degi[node] = dg; dinv[node] = rsqrtf((float)dg + 1.0f); }
  }
}

// ---------------- prefix scan of degrees -> CSR row starts ----------------
static __global__ void k_scanA(const int* __restrict__ degi, int* __restrict__ bsum) {
  __shared__ int tmp[256];
  int i = blockIdx.x * 256 + threadIdx.x;
  int v = (i < NN) ? degi[i] : 0;
  tmp[threadIdx.x] = v;
  __syncthreads();
  for (int off = 128; off > 0; off >>= 1) {
    if (threadIdx.x < off) tmp[threadIdx.x] += tmp[threadIdx.x + off];
    __syncthreads();
  }
  if (threadIdx.x == 0) bsum[blockIdx.x] = tmp[0];
}

static __global__ void k_scanB(const int* __restrict__ bsum, int* __restrict__ bbase2) {
  __shared__ int tmp[512];
  int t = threadIdx.x;
  int v = (t < NBLK) ? bsum[t] : 0;
  tmp[t] = v;
  __syncthreads();
  for (int off = 1; off < 512; off <<= 1) {
    int add = (t >= off) ? tmp[t - off] : 0;
    __syncthreads();
    tmp[t] += add;
    __syncthreads();
  }
  if (t < NBLK) bbase2[t] = tmp[t] - v;  // exclusive
}

static __global__ void k_scanC(const int* __restrict__ degi, const int* __restrict__ bbase2,
                               int* __restrict__ rowstart) {
  __shared__ int tmp[256];
  int i = blockIdx.x * 256 + threadIdx.x;
  int v = (i < NN) ? degi[i] : 0;
  tmp[threadIdx.x] = v;
  __syncthreads();
  for (int off = 1; off < 256; off <<= 1) {
    int add = (threadIdx.x >= off) ? tmp[threadIdx.x - off] : 0;
    __syncthreads();
    tmp[threadIdx.x] += add;
    __syncthreads();
  }
  if (i < NN) rowstart[i] = bbase2[blockIdx.x] + tmp[threadIdx.x] - v;  // exclusive
}

// ------- per-bucket CSR scatter with LDS cursors (localized writes) -----------
static __global__ __launch_bounds__(256) void k_bucket_b(const int2* __restrict__ pairs,
                                                         const int* __restrict__ bbase,
                                                         const int* __restrict__ rowstart,
                                                         int* __restrict__ csr_src) {
  __shared__ int cur[1024];
  int b = blockIdx.x, nb = b << BSHIFT;
  for (int t = threadIdx.x; t < 1024; t += 256) {
    int node = nb + t;
    cur[t] = (node < NN) ? rowstart[node] : 0;
  }
  __syncthreads();
  int p0 = bbase[b], p1 = bbase[b + 1];
  for (int p = p0 + threadIdx.x; p < p1; p += 256) {
    int2 pr = pairs[p];
    int pos = atomicAdd(&cur[pr.y & 1023], 1);
    csr_src[pos] = pr.x;
  }
}

// -------- GEMM 1: h' = dinv * (x @ W1)  (one row per wave, lane = out ch) -----
static __global__ __launch_bounds__(256) void k_gemm1(const float* __restrict__ x,
                                                      const float* __restrict__ W,
                                                      const float* __restrict__ dinv,
                                                      float* __restrict__ h) {
  __shared__ float Ws[CIN * CH];
  for (int t = threadIdx.x; t < CIN * CH; t += 256) Ws[t] = W[t];
  __syncthreads();
  int wave = threadIdx.x >> 6;
  int lane = threadIdx.x & 63;
  int row = blockIdx.x * 4 + wave;  // grid exact: 25000*4
  const float4* xr = reinterpret_cast<const float4*>(x + row * CIN);
  float acc = 0.0f;
#pragma unroll
  for (int k4 = 0; k4 < CIN / 4; ++k4) {
    float4 xv = xr[k4];
    acc += xv.x * Ws[(k4 * 4 + 0) * CH + lane];
    acc += xv.y * Ws[(k4 * 4 + 1) * CH + lane];
    acc += xv.z * Ws[(k4 * 4 + 2) * CH + lane];
    acc += xv.w * Ws[(k4 * 4 + 3) * CH + lane];
  }
  h[row * CH + lane] = acc * dinv[row];
}

// ------- layer-1 agg: agg[i] = dinv[i] * (h'[i] + sum_{s in N(i)} h'[s]) ------
static __global__ __launch_bounds__(256) void k_agg64(const float* __restrict__ h,
                                                      const float* __restrict__ dinv,
                                                      const int* __restrict__ rowstart,
                                                      const int* __restrict__ degi,
                                                      const int* __restrict__ csr_src,
                                                      float* __restrict__ agg) {
  int wave = threadIdx.x >> 6, lane = threadIdx.x & 63;
  int i = blockIdx.x * 4 + wave;  // grid exact: 25000*4
  float acc = h[i * CH + lane];   // self-loop (h already dinv-scaled)
  int s0 = rowstart[i], n = degi[i];
  int k = 0;
  for (; k + 3 < n; k += 4) {
    int sA = csr_src[s0 + k];
    int sB = csr_src[s0 + k + 1];
    int sC = csr_src[s0 + k + 2];
    int sD = csr_src[s0 + k + 3];
    float a = h[sA * CH + lane];
    float b = h[sB * CH + lane];
    float c = h[sC * CH + lane];
    float d = h[sD * CH + lane];
    acc += (a + b) + (c + d);
  }
  for (; k < n; ++k) acc += h[csr_src[s0 + k] * CH + lane];
  agg[i * CH + lane] = acc * dinv[i];
}

// ------ GEMM 2: h2' = dinv * (relu(agg1 + b1) @ W2) (half-wave per row) -------
static __global__ __launch_bounds__(256) void k_gemm2(const float* __restrict__ agg1,
                                                      const float* __restrict__ W,
                                                      const float* __restrict__ b1,
                                                      const float* __restrict__ dinv,
                                                      float* __restrict__ h2) {
  __shared__ float Ws[CH * CO];
  __shared__ float bs[CH];
  for (int t = threadIdx.x; t < CH * CO; t += 256) Ws[t] = W[t];
  if (threadIdx.x < CH) bs[threadIdx.x] = b1[threadIdx.x];
  __syncthreads();
  int half = threadIdx.x >> 5;
  int j = threadIdx.x & 31;
  int row = blockIdx.x * 8 + half;  // grid exact: 12500*8
  const float4* ar = reinterpret_cast<const float4*>(agg1 + row * CH);
  float acc = 0.0f;
#pragma unroll
  for (int k4 = 0; k4 < CH / 4; ++k4) {
    float4 av = ar[k4];
    float v0 = av.x + bs[k4 * 4 + 0]; v0 = v0 > 0.f ? v0 : 0.f;
    float v1 = av.y + bs[k4 * 4 + 1]; v1 = v1 > 0.f ? v1 : 0.f;
    float v2 = av.z + bs[k4 * 4 + 2]; v2 = v2 > 0.f ? v2 : 0.f;
    float v3 = av.w + bs[k4 * 4 + 3]; v3 = v3 > 0.f ? v3 : 0.f;
    acc += v0 * Ws[(k4 * 4 + 0) * CO + j];
    acc += v1 * Ws[(k4 * 4 + 1) * CO + j];
    acc += v2 * Ws[(k4 * 4 + 2) * CO + j];
    acc += v3 * Ws[(k4 * 4 + 3) * CO + j];
  }
  h2[row * CO + j] = acc * dinv[row];
}

// ---- layer-2 agg + bias + mean-pool partial (LDS run-reduction) --------------
static __global__ __launch_bounds__(256) void k_agg32pool(const float* __restrict__ h2,
                                                          const float* __restrict__ dinv,
                                                          const int* __restrict__ rowstart,
                                                          const int* __restrict__ degi,
                                                          const int* __restrict__ csr_src,
                                                          const int* __restrict__ batch,
                                                          const float* __restrict__ b2,
                                                          float* __restrict__ sums) {
  __shared__ float vals[8][CO];
  __shared__ int gid[8];
  int half = threadIdx.x >> 5;  // 0..7 (node slot)
  int c = threadIdx.x & 31;
  int i = blockIdx.x * 8 + half;  // grid exact: 12500*8
  float acc = h2[i * CO + c];     // self-loop (h2 already dinv-scaled)
  int s0 = rowstart[i], n = degi[i];
  int k = 0;
  for (; k + 3 < n; k += 4) {
    int sA = csr_src[s0 + k];
    int sB = csr_src[s0 + k + 1];
    int sC = csr_src[s0 + k + 2];
    int sD = csr_src[s0 + k + 3];
    float a = h2[sA * CO + c];
    float b = h2[sB * CO + c];
    float cc = h2[sC * CO + c];
    float d = h2[sD * CO + c];
    acc += (a + b) + (cc + d);
  }
  for (; k < n; ++k) acc += h2[csr_src[s0 + k] * CO + c];
  vals[half][c] = acc * dinv[i] + b2[c];
  if (c == 0) gid[half] = batch[i];
  __syncthreads();
  if (threadIdx.x < 32) {
    int ch = threadIdx.x;
    float run = vals[0][ch];
    int g = gid[0];
    for (int s = 1; s < 8; ++s) {
      if (gid[s] == g) run += vals[s][ch];
      else { atomicAdd(&sums[g * CO + ch], run); g = gid[s]; run = vals[s][ch]; }
    }
    atomicAdd(&sums[g * CO + ch], run);
  }
}

static __global__ void k_final(const float* __restrict__ sums, const float* __restrict__ counts,
                               float* __restrict__ out) {
  int t = blockIdx.x * 256 + threadIdx.x;
  if (t >= NG * CO) return;
  out[t] = sums[t] / fmaxf(counts[t >> 5], 1.0f);
}

extern "C" void kernel_launch(void* const* d_in, const int* in_sizes, int n_in,
                              void* d_out, int out_size, void* d_ws, size_t ws_size,
                              hipStream_t stream) {
  const float* x   = (const float*)d_in[0];
  const int* ei    = (const int*)d_in[1];   // [2, NE]: src = ei, dst = ei+NE
  const int* batch = (const int*)d_in[2];
  const float* W1  = (const float*)d_in[3];
  const float* b1  = (const float*)d_in[4];
  const float* W2  = (const float*)d_in[5];
  const float* b2  = (const float*)d_in[6];
  float* out = (float*)d_out;

  const int* src = ei;
  const int* dst = ei + NE;

  char* base = (char*)d_ws;
  size_t off = 0;
  auto alloc = [&](size_t nelem) {
    void* p = (void*)(base + off);
    off += ((nelem * 4 + 255) / 256) * 256;
    return p;
  };
  int* degi      = (int*)alloc(NN);
  int* rowstart  = (int*)alloc(NN);
  float* dinv    = (float*)alloc(NN);
  int* bsum      = (int*)alloc(NBLK);
  int* bbase2    = (int*)alloc(NBLK);
  int* bhist     = (int*)alloc(128);
  int* bbase     = (int*)alloc(129);
  int* bcursor   = (int*)alloc(128);
  int* csr_src   = (int*)alloc(NE);                 // 5 MB
  float* bufA    = (float*)alloc((size_t)NN * CH);  // h1' then h2'
  float* bufB    = (float*)alloc((size_t)NN * CH);  // pairs (10 MB) then agg1
  float* sums    = (float*)alloc(NG * CO);
  float* counts  = (float*)alloc(NG);
  int2* pairs    = (int2*)bufB;  // dead once k_bucket_b finishes; agg64 then owns bufB

  dim3 B(256);
  // CSR build (bucketed, cache-friendly)
  k_zero<<<dim3(16), B, 0, stream>>>(sums, bhist, batch, counts);
  k_bhist<<<dim3(NBLKP), B, 0, stream>>>(dst, bhist);
  k_bscan<<<dim3(1), dim3(128), 0, stream>>>(bhist, bbase, bcursor);
  k_part<<<dim3(NBLKP), B, 0, stream>>>(src, dst, bcursor, pairs);
  k_bucket_a<<<dim3(NBUCK), B, 0, stream>>>(pairs, bbase, degi, dinv);
  k_scanA<<<dim3(NBLK), B, 0, stream>>>(degi, bsum);
  k_scanB<<<dim3(1), dim3(512), 0, stream>>>(bsum, bbase2);
  k_scanC<<<dim3(NBLK), B, 0, stream>>>(degi, bbase2, rowstart);
  k_bucket_b<<<dim3(NBUCK), B, 0, stream>>>(pairs, bbase, rowstart, csr_src);
  // layer 1
  k_gemm1<<<dim3(NN / 4), B, 0, stream>>>(x, W1, dinv, bufA);
  k_agg64<<<dim3(NN / 4), B, 0, stream>>>(bufA, dinv, rowstart, degi, csr_src, bufB);
  // layer 2
  k_gemm2<<<dim3(NN / 8), B, 0, stream>>>(bufB, W2, b1, dinv, bufA);
  k_agg32pool<<<dim3(NN / 8), B, 0, stream>>>(bufA, dinv, rowstart, degi, csr_src, batch, b2, sums);
  // finalize
  k_final<<<dim3((NG * CO + 255) / 256), B, 0, stream>>>(sums, counts, out);
}